// Round 1
// baseline (155.409 us; speedup 1.0000x reference)
//
#include <hip/hip_runtime.h>
#include <math.h>

// loss = -sum_ij d1[i,j] * log(d2[i,j] + 1e-5), fp32 in, scalar fp32 out.
// Memory-bound: 134 MB read @ ~6.3 TB/s -> ~21 us floor.

#define EPS 1e-5f

__global__ void cep_zero_kernel(float* out) {
    out[0] = 0.0f;
}

__global__ __launch_bounds__(256) void cep_loss_kernel(
        const float4* __restrict__ d1,
        const float4* __restrict__ d2,
        float* __restrict__ out,
        int n4) {
    int tid = blockIdx.x * blockDim.x + threadIdx.x;
    int stride = gridDim.x * blockDim.x;

    float acc = 0.0f;
    for (int i = tid; i < n4; i += stride) {
        float4 a = d1[i];
        float4 b = d2[i];
        acc += a.x * __logf(b.x + EPS);
        acc += a.y * __logf(b.y + EPS);
        acc += a.z * __logf(b.z + EPS);
        acc += a.w * __logf(b.w + EPS);
    }

    // wave-64 shuffle reduction
    #pragma unroll
    for (int off = 32; off > 0; off >>= 1)
        acc += __shfl_down(acc, off, 64);

    __shared__ float wave_sums[4];  // 256 threads / 64 lanes
    int lane = threadIdx.x & 63;
    int wid  = threadIdx.x >> 6;
    if (lane == 0) wave_sums[wid] = acc;
    __syncthreads();

    if (threadIdx.x == 0) {
        float s = wave_sums[0] + wave_sums[1] + wave_sums[2] + wave_sums[3];
        atomicAdd(out, -s);  // device-scope by default on CDNA
    }
}

extern "C" void kernel_launch(void* const* d_in, const int* in_sizes, int n_in,
                              void* d_out, int out_size, void* d_ws, size_t ws_size,
                              hipStream_t stream) {
    const float4* d1 = (const float4*)d_in[0];
    const float4* d2 = (const float4*)d_in[1];
    float* out = (float*)d_out;

    int n = in_sizes[0];        // 4096*4096 = 16,777,216 (divisible by 4)
    int n4 = n / 4;             // 4,194,304 float4 elements

    cep_zero_kernel<<<1, 1, 0, stream>>>(out);

    const int block = 256;
    const int grid = 2048;      // 8 blocks/CU worth of waves; 8 float4 iters/thread
    cep_loss_kernel<<<grid, block, 0, stream>>>(d1, d2, out, n4);
}